// Round 1
// baseline (2293.833 us; speedup 1.0000x reference)
//
#include <hip/hip_runtime.h>

typedef __attribute__((ext_vector_type(4))) float f32x4;
typedef __attribute__((ext_vector_type(8))) short s16x8;
typedef __attribute__((ext_vector_type(4))) short s16x4;
typedef __attribute__((ext_vector_type(4))) int i32x4;

__device__ __forceinline__ short f2bf(float f) {
  union { float f; unsigned u; } v; v.f = f;
  unsigned r = (v.u + 0x7fffu + ((v.u >> 16) & 1u)) >> 16;
  return (short)(r & 0xffffu);
}

__device__ __forceinline__ f32x4 mfma16(s16x8 a, s16x8 b, f32x4 c) {
  return __builtin_amdgcn_mfma_f32_16x16x32_bf16(a, b, c, 0, 0, 0);
}

#define AS1(p) ((__attribute__((address_space(1))) void*)(p))
#define AS3(p) ((__attribute__((address_space(3))) void*)(p))

// ---------------- fp32 -> bf16 convert ----------------
__global__ __launch_bounds__(256) void cvt_bf16_kernel(const float* __restrict__ in,
                                                       short* __restrict__ out, long n) {
  long i = ((long)blockIdx.x * 256 + threadIdx.x) * 4;
  if (i + 4 <= n) {
    f32x4 v = *(const f32x4*)(in + i);
    s16x4 o;
    o[0] = f2bf(v[0]); o[1] = f2bf(v[1]); o[2] = f2bf(v[2]); o[3] = f2bf(v[3]);
    *(s16x4*)(out + i) = o;
  }
}

// ---------------- rel table prep ----------------
// relqb/relkb: (16, 240, 64) bf16, rows >=225 zeroed.
// relvT:       (16, 64, 256) bf16, relvT[h][d][r] = rel_v[h][r][d], r>=225 zeroed.
// Dh:          (16, 240) f32, Dh[h][r] = sum_d rel_q[h,r,d]*rel_k[h,r,d].
__global__ __launch_bounds__(64) void prep_rel_kernel(
    const float* __restrict__ rq, const float* __restrict__ rk, const float* __restrict__ rv,
    short* __restrict__ relqb, short* __restrict__ relkb, short* __restrict__ relvT,
    float* __restrict__ Dh) {
  int h = blockIdx.x / 240;
  int r = blockIdx.x % 240;
  int d = threadIdx.x;
  float vq = 0.f, vk = 0.f, vv = 0.f;
  if (r < 225) {
    long o = ((long)h * 225 + r) * 64 + d;
    vq = rq[o]; vk = rk[o]; vv = rv[o];
  }
  relqb[((long)h * 240 + r) * 64 + d] = f2bf(vq);
  relkb[((long)h * 240 + r) * 64 + d] = f2bf(vk);
  relvT[((long)h * 64 + d) * 256 + r] = f2bf(vv);
  if (r < 16) relvT[((long)h * 64 + d) * 256 + 240 + r] = 0;
  float p = vq * vk;
  #pragma unroll
  for (int m = 32; m >= 1; m >>= 1) p += __shfl_xor(p, m);
  if (d == 0) Dh[h * 240 + r] = p;
}

// ---------------- C = A(MxK) @ Bw(NxK)^T + bias, 128x128 tile ----------------
template<int OUT_BF16>
__global__ __launch_bounds__(256) void gemm_bt_kernel(
    const short* __restrict__ A, const short* __restrict__ Bw,
    const float* __restrict__ bias, void* __restrict__ Cout,
    int M, int N, int K) {
  __shared__ __attribute__((aligned(16))) short As[4096];  // 128 x 32
  __shared__ __attribute__((aligned(16))) short Bs[4096];  // 128 x 32
  const int tid = threadIdx.x;
  const int lane = tid & 63;
  const int w = tid >> 6;
  const int wr = w >> 1, wc = w & 1;
  const int l15 = lane & 15, l4 = lane >> 4;
  const int nbn = N >> 7;
  const int nwg = gridDim.x;
  const int bid = blockIdx.x;
  const int swz = ((bid & 7) * (nwg >> 3)) + (bid >> 3);   // XCD swizzle (nwg%8==0)
  const int bm = swz / nbn, bn = swz % nbn;

  const int sr = w * 32 + (lane >> 2);   // staging row within 128
  const int sc = (lane & 3) * 8;         // staging col within 32
  const short* ga0 = A  + ((long)(bm * 128 + sr)) * K + sc;
  const short* gb0 = Bw + ((long)(bn * 128 + sr)) * K + sc;
  const long row16 = (long)16 * K;
  short* la0 = As + w * 1024;
  short* lb0 = Bs + w * 1024;

  f32x4 zero = {0.f, 0.f, 0.f, 0.f};
  f32x4 acc[4][4];
  #pragma unroll
  for (int mi = 0; mi < 4; mi++)
    #pragma unroll
    for (int nj = 0; nj < 4; nj++) acc[mi][nj] = zero;

  for (int k0 = 0; k0 < K; k0 += 32) {
    __builtin_amdgcn_global_load_lds(AS1(ga0 + k0),         AS3(la0),       16, 0, 0);
    __builtin_amdgcn_global_load_lds(AS1(ga0 + row16 + k0), AS3(la0 + 512), 16, 0, 0);
    __builtin_amdgcn_global_load_lds(AS1(gb0 + k0),         AS3(lb0),       16, 0, 0);
    __builtin_amdgcn_global_load_lds(AS1(gb0 + row16 + k0), AS3(lb0 + 512), 16, 0, 0);
    __syncthreads();
    s16x8 af[4], bfv[4];
    #pragma unroll
    for (int mi = 0; mi < 4; mi++)
      af[mi] = *(const s16x8*)&As[(wr * 64 + mi * 16 + l15) * 32 + l4 * 8];
    #pragma unroll
    for (int nj = 0; nj < 4; nj++)
      bfv[nj] = *(const s16x8*)&Bs[(wc * 64 + nj * 16 + l15) * 32 + l4 * 8];
    #pragma unroll
    for (int mi = 0; mi < 4; mi++)
      #pragma unroll
      for (int nj = 0; nj < 4; nj++)
        acc[mi][nj] = mfma16(af[mi], bfv[nj], acc[mi][nj]);
    __syncthreads();
  }

  const long crow = (long)bm * 128 + wr * 64;
  const int ccol = bn * 128 + wc * 64;
  #pragma unroll
  for (int nj = 0; nj < 4; nj++) {
    const int col = ccol + nj * 16 + l15;
    const float bv = bias[col];
    #pragma unroll
    for (int mi = 0; mi < 4; mi++) {
      #pragma unroll
      for (int j = 0; j < 4; j++) {
        const long row = crow + mi * 16 + l4 * 4 + j;
        float val = acc[mi][nj][j] + bv;
        if (OUT_BF16) ((short*)Cout)[row * N + col] = f2bf(val);
        else          ((float*)Cout)[row * N + col] = val;
      }
    }
  }
}

// ---------------- fused relative attention, one block per (b,h) ----------------
__global__ __launch_bounds__(256) void attn_kernel(
    const short* __restrict__ qg, const short* __restrict__ kg, const short* __restrict__ vg,
    const short* __restrict__ relqb, const short* __restrict__ relkb,
    const short* __restrict__ relvT, const float* __restrict__ Dh,
    const int* __restrict__ rel_index, short* __restrict__ outA) {
  __shared__ __attribute__((aligned(16))) short qs[4096];   // q[t][d], later attn[t][s]
  __shared__ __attribute__((aligned(16))) short ks[4096];   // k[s][d]
  __shared__ __attribute__((aligned(16))) short vts[4096];  // v^T[d][s]
  __shared__ __attribute__((aligned(16))) float buf[16384]; // 64 x 256: qr -> kr -> P
  __shared__ __attribute__((aligned(16))) int idxs[4096];
  __shared__ float Ds[240];

  const int tid = threadIdx.x;
  const int lane = tid & 63;
  const int w = tid >> 6;
  const int l15 = lane & 15, l4 = lane >> 4;
  const int bh = blockIdx.x;
  const int b = bh >> 4, h = bh & 15;
  f32x4 zero = {0.f, 0.f, 0.f, 0.f};

  // stage q, k row-major; v transposed; idx; D table
  {
    const int t = tid >> 2;
    const int c0 = (tid & 3) * 16;
    const long gbase = ((long)(b * 64 + t)) * 1024 + h * 64 + c0;
    s16x8 q0 = *(const s16x8*)(qg + gbase);
    s16x8 q1 = *(const s16x8*)(qg + gbase + 8);
    *(s16x8*)&qs[t * 64 + c0] = q0;
    *(s16x8*)&qs[t * 64 + c0 + 8] = q1;
    s16x8 kk0 = *(const s16x8*)(kg + gbase);
    s16x8 kk1 = *(const s16x8*)(kg + gbase + 8);
    *(s16x8*)&ks[t * 64 + c0] = kk0;
    *(s16x8*)&ks[t * 64 + c0 + 8] = kk1;
    s16x8 v0 = *(const s16x8*)(vg + gbase);
    s16x8 v1 = *(const s16x8*)(vg + gbase + 8);
    #pragma unroll
    for (int i = 0; i < 8; i++) vts[(c0 + i) * 64 + t] = v0[i];
    #pragma unroll
    for (int i = 0; i < 8; i++) vts[(c0 + 8 + i) * 64 + t] = v1[i];
    const i32x4* isrc = (const i32x4*)rel_index;
    i32x4* idst = (i32x4*)idxs;
    #pragma unroll
    for (int i = 0; i < 4; i++) idst[tid + 256 * i] = isrc[tid + 256 * i];
    if (tid < 240) Ds[tid] = Dh[h * 240 + tid];
  }
  __syncthreads();

  // S = q @ k^T  (wave w owns t-rows [16w, 16w+16))
  f32x4 sacc[4];
  sacc[0] = sacc[1] = sacc[2] = sacc[3] = zero;
  s16x8 aq0 = *(const s16x8*)&qs[(w * 16 + l15) * 64 + l4 * 8];
  s16x8 aq1 = *(const s16x8*)&qs[(w * 16 + l15) * 64 + 32 + l4 * 8];
  #pragma unroll
  for (int n = 0; n < 4; n++) {
    s16x8 b0 = *(const s16x8*)&ks[(n * 16 + l15) * 64 + l4 * 8];
    s16x8 b1 = *(const s16x8*)&ks[(n * 16 + l15) * 64 + 32 + l4 * 8];
    sacc[n] = mfma16(aq0, b0, sacc[n]);
    sacc[n] = mfma16(aq1, b1, sacc[n]);
  }
  // qr = q @ rel_k[h]^T  -> buf rows t
  {
    const short* rkh = relkb + h * 240 * 64;
    #pragma unroll
    for (int n = 0; n < 15; n++) {
      s16x8 b0 = *(const s16x8*)&rkh[(n * 16 + l15) * 64 + l4 * 8];
      s16x8 b1 = *(const s16x8*)&rkh[(n * 16 + l15) * 64 + 32 + l4 * 8];
      f32x4 t0 = zero;
      t0 = mfma16(aq0, b0, t0);
      t0 = mfma16(aq1, b1, t0);
      #pragma unroll
      for (int j = 0; j < 4; j++)
        buf[(w * 16 + l4 * 4 + j) * 256 + n * 16 + l15] = t0[j];
    }
  }
  __syncthreads();
  // gather qr
  #pragma unroll
  for (int n = 0; n < 4; n++)
    #pragma unroll
    for (int j = 0; j < 4; j++) {
      const int t = w * 16 + l4 * 4 + j;
      const int s = n * 16 + l15;
      sacc[n][j] += buf[t * 256 + idxs[t * 64 + s]];
    }
  __syncthreads();
  // kr = k @ rel_q[h]^T  -> buf rows s
  {
    const short* rqh = relqb + h * 240 * 64;
    s16x8 ak0 = *(const s16x8*)&ks[(w * 16 + l15) * 64 + l4 * 8];
    s16x8 ak1 = *(const s16x8*)&ks[(w * 16 + l15) * 64 + 32 + l4 * 8];
    #pragma unroll
    for (int n = 0; n < 15; n++) {
      s16x8 b0 = *(const s16x8*)&rqh[(n * 16 + l15) * 64 + l4 * 8];
      s16x8 b1 = *(const s16x8*)&rqh[(n * 16 + l15) * 64 + 32 + l4 * 8];
      f32x4 t0 = zero;
      t0 = mfma16(ak0, b0, t0);
      t0 = mfma16(ak1, b1, t0);
      #pragma unroll
      for (int j = 0; j < 4; j++)
        buf[(w * 16 + l4 * 4 + j) * 256 + n * 16 + l15] = t0[j];
    }
  }
  __syncthreads();
  // gather kr + D, scale, softmax
  const float scale = 0.125f;
  float att[4][4];
  #pragma unroll
  for (int n = 0; n < 4; n++)
    #pragma unroll
    for (int j = 0; j < 4; j++) {
      const int t = w * 16 + l4 * 4 + j;
      const int s = n * 16 + l15;
      const int r = idxs[t * 64 + s];
      sacc[n][j] = (sacc[n][j] + buf[s * 256 + r] + Ds[r]) * scale;
    }
  #pragma unroll
  for (int j = 0; j < 4; j++) {
    float m = fmaxf(fmaxf(sacc[0][j], sacc[1][j]), fmaxf(sacc[2][j], sacc[3][j]));
    m = fmaxf(m, __shfl_xor(m, 1));
    m = fmaxf(m, __shfl_xor(m, 2));
    m = fmaxf(m, __shfl_xor(m, 4));
    m = fmaxf(m, __shfl_xor(m, 8));
    float sum = 0.f;
    #pragma unroll
    for (int n = 0; n < 4; n++) { att[n][j] = __expf(sacc[n][j] - m); sum += att[n][j]; }
    sum += __shfl_xor(sum, 1);
    sum += __shfl_xor(sum, 2);
    sum += __shfl_xor(sum, 4);
    sum += __shfl_xor(sum, 8);
    const float inv = 1.f / sum;
    #pragma unroll
    for (int n = 0; n < 4; n++) att[n][j] *= inv;
  }
  __syncthreads();           // all buf(kr) reads done
  // zero P, write attn(bf16) into qs
  #pragma unroll
  for (int i = 0; i < 64; i++) buf[i * 256 + tid] = 0.f;
  #pragma unroll
  for (int n = 0; n < 4; n++)
    #pragma unroll
    for (int j = 0; j < 4; j++) {
      const int t = w * 16 + l4 * 4 + j;
      const int s = n * 16 + l15;
      qs[t * 64 + s] = f2bf(att[n][j]);
    }
  __syncthreads();
  // scatter P[t][r] += attn
  #pragma unroll
  for (int n = 0; n < 4; n++)
    #pragma unroll
    for (int j = 0; j < 4; j++) {
      const int t = w * 16 + l4 * 4 + j;
      const int s = n * 16 + l15;
      atomicAdd(&buf[t * 256 + idxs[t * 64 + s]], att[n][j]);
    }
  __syncthreads();
  // out = attn @ v + P @ rel_v[h]
  f32x4 oacc[4];
  oacc[0] = oacc[1] = oacc[2] = oacc[3] = zero;
  s16x8 pa0 = *(const s16x8*)&qs[(w * 16 + l15) * 64 + l4 * 8];
  s16x8 pa1 = *(const s16x8*)&qs[(w * 16 + l15) * 64 + 32 + l4 * 8];
  #pragma unroll
  for (int n = 0; n < 4; n++) {
    s16x8 b0 = *(const s16x8*)&vts[(n * 16 + l15) * 64 + l4 * 8];
    s16x8 b1 = *(const s16x8*)&vts[(n * 16 + l15) * 64 + 32 + l4 * 8];
    oacc[n] = mfma16(pa0, b0, oacc[n]);
    oacc[n] = mfma16(pa1, b1, oacc[n]);
  }
  const short* rvh = relvT + h * 64 * 256;
  #pragma unroll
  for (int kk = 0; kk < 8; kk++) {
    f32x4 p0 = *(const f32x4*)&buf[(w * 16 + l15) * 256 + kk * 32 + l4 * 8];
    f32x4 p1 = *(const f32x4*)&buf[(w * 16 + l15) * 256 + kk * 32 + l4 * 8 + 4];
    s16x8 pa;
    #pragma unroll
    for (int i = 0; i < 4; i++) { pa[i] = f2bf(p0[i]); pa[4 + i] = f2bf(p1[i]); }
    #pragma unroll
    for (int n = 0; n < 4; n++) {
      s16x8 bb = *(const s16x8*)&rvh[(n * 16 + l15) * 256 + kk * 32 + l4 * 8];
      oacc[n] = mfma16(pa, bb, oacc[n]);
    }
  }
  #pragma unroll
  for (int n = 0; n < 4; n++)
    #pragma unroll
    for (int j = 0; j < 4; j++) {
      const int t = w * 16 + l4 * 4 + j;
      const int d = n * 16 + l15;
      outA[((long)(b * 64 + t)) * 1024 + h * 64 + d] = f2bf(oacc[n][j]);
    }
}

extern "C" void kernel_launch(void* const* d_in, const int* in_sizes, int n_in,
                              void* d_out, int out_size, void* d_ws, size_t ws_size,
                              hipStream_t stream) {
  const float* x     = (const float*)d_in[0];
  const float* Wq_w  = (const float*)d_in[1];
  const float* Wq_b  = (const float*)d_in[2];
  const float* Wk_w  = (const float*)d_in[3];
  const float* Wk_b  = (const float*)d_in[4];
  const float* Wv_w  = (const float*)d_in[5];
  const float* Wv_b  = (const float*)d_in[6];
  const float* Wo_w  = (const float*)d_in[7];
  const float* Wo_b  = (const float*)d_in[8];
  const float* rel_q = (const float*)d_in[9];
  const float* rel_k = (const float*)d_in[10];
  const float* rel_v = (const float*)d_in[11];
  const int* rel_index = (const int*)d_in[12];
  float* out = (float*)d_out;

  char* ws = (char*)d_ws;
  short* x_bf  = (short*)(ws);                  // 134,217,728 B
  short* q_bf  = (short*)(ws + 134217728L);
  short* k_bf  = (short*)(ws + 268435456L);
  short* v_bf  = (short*)(ws + 402653184L);
  short* wq_bf = (short*)(ws + 536870912L);
  short* wk_bf = (short*)(ws + 538968064L);
  short* wv_bf = (short*)(ws + 541065216L);
  short* wo_bf = (short*)(ws + 543162368L);
  short* relqb = (short*)(ws + 545259520L);
  short* relkb = (short*)(ws + 545751040L);
  short* relvT = (short*)(ws + 546242560L);
  float* Dh    = (float*)(ws + 546766848L);
  short* a_bf  = x_bf;  // reuse: x_bf dead after QKV GEMMs

  cvt_bf16_kernel<<<65536, 256, 0, stream>>>(x, x_bf, 67108864L);
  cvt_bf16_kernel<<<1024, 256, 0, stream>>>(Wq_w, wq_bf, 1048576L);
  cvt_bf16_kernel<<<1024, 256, 0, stream>>>(Wk_w, wk_bf, 1048576L);
  cvt_bf16_kernel<<<1024, 256, 0, stream>>>(Wv_w, wv_bf, 1048576L);
  cvt_bf16_kernel<<<1024, 256, 0, stream>>>(Wo_w, wo_bf, 1048576L);
  prep_rel_kernel<<<3840, 64, 0, stream>>>(rel_q, rel_k, rel_v, relqb, relkb, relvT, Dh);
  gemm_bt_kernel<1><<<4096, 256, 0, stream>>>(x_bf, wq_bf, Wq_b, (void*)q_bf, 65536, 1024, 1024);
  gemm_bt_kernel<1><<<4096, 256, 0, stream>>>(x_bf, wk_bf, Wk_b, (void*)k_bf, 65536, 1024, 1024);
  gemm_bt_kernel<1><<<4096, 256, 0, stream>>>(x_bf, wv_bf, Wv_b, (void*)v_bf, 65536, 1024, 1024);
  attn_kernel<<<16384, 256, 0, stream>>>(q_bf, k_bf, v_bf, relqb, relkb, relvT, Dh,
                                         rel_index, a_bf);
  gemm_bt_kernel<0><<<4096, 256, 0, stream>>>(a_bf, wo_bf, Wo_b, (void*)out, 65536, 1024, 1024);
}

// Round 2
// 1896.066 us; speedup vs baseline: 1.2098x; 1.2098x over previous
//
#include <hip/hip_runtime.h>

typedef __attribute__((ext_vector_type(4))) float f32x4;
typedef __attribute__((ext_vector_type(8))) short s16x8;
typedef __attribute__((ext_vector_type(4))) short s16x4;
typedef __attribute__((ext_vector_type(4))) int i32x4;

__device__ __forceinline__ short f2bf(float f) {
  union { float f; unsigned u; } v; v.f = f;
  unsigned r = (v.u + 0x7fffu + ((v.u >> 16) & 1u)) >> 16;
  return (short)(r & 0xffffu);
}
__device__ __forceinline__ float bf2f(short s) {
  union { unsigned u; float f; } v; v.u = ((unsigned)(unsigned short)s) << 16;
  return v.f;
}
__device__ __forceinline__ f32x4 mfma16(s16x8 a, s16x8 b, f32x4 c) {
  return __builtin_amdgcn_mfma_f32_16x16x32_bf16(a, b, c, 0, 0, 0);
}

#define AS1(p) ((__attribute__((address_space(1))) void*)(p))
#define AS3(p) ((__attribute__((address_space(3))) void*)(p))

// ---------------- fp32 -> bf16 convert ----------------
__global__ __launch_bounds__(256) void cvt_bf16_kernel(const float* __restrict__ in,
                                                       short* __restrict__ out, long n) {
  long i = ((long)blockIdx.x * 256 + threadIdx.x) * 4;
  if (i + 4 <= n) {
    f32x4 v = *(const f32x4*)(in + i);
    s16x4 o;
    o[0] = f2bf(v[0]); o[1] = f2bf(v[1]); o[2] = f2bf(v[2]); o[3] = f2bf(v[3]);
    *(s16x4*)(out + i) = o;
  }
}

// ---------------- concat 3 bias vectors (1024 each) ----------------
__global__ __launch_bounds__(256) void bias_cat_kernel(const float* __restrict__ bq,
                                                       const float* __restrict__ bk,
                                                       const float* __restrict__ bv,
                                                       float* __restrict__ o) {
  int i = blockIdx.x * 256 + threadIdx.x;
  if (i < 3072) o[i] = (i < 1024) ? bq[i] : ((i < 2048) ? bk[i - 1024] : bv[i - 2048]);
}

// ---------------- rel table prep ----------------
__global__ __launch_bounds__(64) void prep_rel_kernel(
    const float* __restrict__ rq, const float* __restrict__ rk, const float* __restrict__ rv,
    short* __restrict__ relqb, short* __restrict__ relkb, short* __restrict__ relvT,
    float* __restrict__ Dh) {
  int h = blockIdx.x / 240;
  int r = blockIdx.x % 240;
  int d = threadIdx.x;
  float vq = 0.f, vk = 0.f, vv = 0.f;
  if (r < 225) {
    long o = ((long)h * 225 + r) * 64 + d;
    vq = rq[o]; vk = rk[o]; vv = rv[o];
  }
  relqb[((long)h * 240 + r) * 64 + d] = f2bf(vq);
  relkb[((long)h * 240 + r) * 64 + d] = f2bf(vk);
  relvT[((long)h * 64 + d) * 256 + r] = f2bf(vv);
  if (r < 16) relvT[((long)h * 64 + d) * 256 + 240 + r] = 0;
  float p = vq * vk;
  #pragma unroll
  for (int m = 32; m >= 1; m >>= 1) p += __shfl_xor(p, m);
  if (d == 0) Dh[h * 240 + r] = p;
}

// ---------------- C = A(MxK) @ Bw(NxK)^T + bias, 128x128 tile ----------------
template<int OUT_BF16>
__global__ __launch_bounds__(256) void gemm_bt_kernel(
    const short* __restrict__ A, const short* __restrict__ Bw,
    const float* __restrict__ bias, void* __restrict__ Cout,
    int M, int N, int K) {
  __shared__ __attribute__((aligned(16))) short As[4096];  // 128 x 32
  __shared__ __attribute__((aligned(16))) short Bs[4096];  // 128 x 32
  const int tid = threadIdx.x;
  const int lane = tid & 63;
  const int w = tid >> 6;
  const int wr = w >> 1, wc = w & 1;
  const int l15 = lane & 15, l4 = lane >> 4;
  const int nbn = N >> 7;
  const int nwg = gridDim.x;
  const int bid = blockIdx.x;
  const int swz = ((bid & 7) * (nwg >> 3)) + (bid >> 3);   // XCD swizzle (nwg%8==0)
  const int bm = swz / nbn, bn = swz % nbn;

  const int sr = w * 32 + (lane >> 2);
  const int sc = (lane & 3) * 8;
  const short* ga0 = A  + ((long)(bm * 128 + sr)) * K + sc;
  const short* gb0 = Bw + ((long)(bn * 128 + sr)) * K + sc;
  const long row16 = (long)16 * K;
  short* la0 = As + w * 1024;
  short* lb0 = Bs + w * 1024;

  f32x4 zero = {0.f, 0.f, 0.f, 0.f};
  f32x4 acc[4][4];
  #pragma unroll
  for (int mi = 0; mi < 4; mi++)
    #pragma unroll
    for (int nj = 0; nj < 4; nj++) acc[mi][nj] = zero;

  for (int k0 = 0; k0 < K; k0 += 32) {
    __builtin_amdgcn_global_load_lds(AS1(ga0 + k0),         AS3(la0),       16, 0, 0);
    __builtin_amdgcn_global_load_lds(AS1(ga0 + row16 + k0), AS3(la0 + 512), 16, 0, 0);
    __builtin_amdgcn_global_load_lds(AS1(gb0 + k0),         AS3(lb0),       16, 0, 0);
    __builtin_amdgcn_global_load_lds(AS1(gb0 + row16 + k0), AS3(lb0 + 512), 16, 0, 0);
    __syncthreads();
    s16x8 af[4], bfv[4];
    #pragma unroll
    for (int mi = 0; mi < 4; mi++)
      af[mi] = *(const s16x8*)&As[(wr * 64 + mi * 16 + l15) * 32 + l4 * 8];
    #pragma unroll
    for (int nj = 0; nj < 4; nj++)
      bfv[nj] = *(const s16x8*)&Bs[(wc * 64 + nj * 16 + l15) * 32 + l4 * 8];
    #pragma unroll
    for (int mi = 0; mi < 4; mi++)
      #pragma unroll
      for (int nj = 0; nj < 4; nj++)
        acc[mi][nj] = mfma16(af[mi], bfv[nj], acc[mi][nj]);
    __syncthreads();
  }

  const long crow = (long)bm * 128 + wr * 64;
  const int ccol = bn * 128 + wc * 64;
  #pragma unroll
  for (int nj = 0; nj < 4; nj++) {
    const int col = ccol + nj * 16 + l15;
    const float bv = bias[col];
    #pragma unroll
    for (int mi = 0; mi < 4; mi++) {
      #pragma unroll
      for (int j = 0; j < 4; j++) {
        const long row = crow + mi * 16 + l4 * 4 + j;
        float val = acc[mi][nj][j] + bv;
        if (OUT_BF16) ((short*)Cout)[row * N + col] = f2bf(val);
        else          ((float*)Cout)[row * N + col] = val;
      }
    }
  }
}

// ---------------- fused relative attention, one block per (b,h) ----------------
// LDS 50,112 B -> 3 blocks/CU.  All tiles XOR-swizzled: byte ^= (row&7)<<4.
// idx[t,s] is injective in s for fixed t (8x8 grid, no clipping) -> P-scatter
// is collision-free, so P lives in bf16 with plain writes (no atomics).
__global__ __launch_bounds__(256, 3) void attn_kernel(
    const short* __restrict__ qkv, const short* __restrict__ relqb,
    const short* __restrict__ relkb, const short* __restrict__ relvT,
    const float* __restrict__ Dh, const int* __restrict__ rel_index,
    short* __restrict__ outA) {
  __shared__ __attribute__((aligned(16))) char ksb[8192];   // k[s][d] -> later attn[t][s]
  __shared__ __attribute__((aligned(16))) char vtb[8192];   // v^T[d][s]
  __shared__ __attribute__((aligned(16))) char bufb[32768]; // bf16 [64][256]: qr -> kr -> P
  __shared__ float Ds[240];

  const int tid = threadIdx.x, lane = tid & 63, w = tid >> 6;
  const int l15 = lane & 15, l4 = lane >> 4;
  const int bh = blockIdx.x, b = bh >> 4, h = bh & 15;
  const f32x4 zero = {0.f, 0.f, 0.f, 0.f};

  // --- stage k (swizzled rows), v^T (swizzled), Ds
  {
    const int t = tid >> 2, c0 = (tid & 3) * 16;
    const long gbase = ((long)(b * 64 + t)) * 3072 + h * 64 + c0;
    const int tx = (t & 7) << 4;
    s16x8 k0 = *(const s16x8*)(qkv + gbase + 1024);
    s16x8 k1 = *(const s16x8*)(qkv + gbase + 1032);
    *(s16x8*)(ksb + t * 128 + ((c0 * 2) ^ tx)) = k0;
    *(s16x8*)(ksb + t * 128 + ((c0 * 2 + 16) ^ tx)) = k1;
    s16x8 v0 = *(const s16x8*)(qkv + gbase + 2048);
    s16x8 v1 = *(const s16x8*)(qkv + gbase + 2056);
    #pragma unroll
    for (int i = 0; i < 8; i++) {
      int d = c0 + i;
      *(short*)(vtb + d * 128 + ((t * 2) ^ ((d & 7) << 4))) = v0[i];
    }
    #pragma unroll
    for (int i = 0; i < 8; i++) {
      int d = c0 + 8 + i;
      *(short*)(vtb + d * 128 + ((t * 2) ^ ((d & 7) << 4))) = v1[i];
    }
    if (tid < 240) Ds[tid] = Dh[h * 240 + tid];
  }
  __syncthreads();   // barrier A

  // per-lane idx registers: the 16 (t,s) pairs this lane owns in C-layout
  int idxr[16];
  #pragma unroll
  for (int n = 0; n < 4; n++)
    #pragma unroll
    for (int j = 0; j < 4; j++)
      idxr[n * 4 + j] = rel_index[(w * 16 + l4 * 4 + j) * 64 + n * 16 + l15];

  // q A-fragments straight from global
  const int tq = w * 16 + l15;
  const long qrow = ((long)(b * 64 + tq)) * 3072 + h * 64;
  s16x8 aq0 = *(const s16x8*)(qkv + qrow + l4 * 8);
  s16x8 aq1 = *(const s16x8*)(qkv + qrow + 32 + l4 * 8);

  // S = q @ k^T
  f32x4 sacc[4];
  sacc[0] = sacc[1] = sacc[2] = sacc[3] = zero;
  #pragma unroll
  for (int n = 0; n < 4; n++) {
    const int row = n * 16 + l15, rx = (row & 7) << 4;
    s16x8 b0 = *(const s16x8*)(ksb + row * 128 + ((l4 * 16) ^ rx));
    s16x8 b1 = *(const s16x8*)(ksb + row * 128 + ((64 + l4 * 16) ^ rx));
    sacc[n] = mfma16(aq0, b0, sacc[n]);
    sacc[n] = mfma16(aq1, b1, sacc[n]);
  }

  // qr = q @ rel_k[h]^T -> buf own rows (bf16, swizzled)
  {
    const short* rkh = relkb + h * 240 * 64;
    #pragma unroll
    for (int n = 0; n < 15; n++) {
      const int rr = n * 16 + l15;
      s16x8 b0 = *(const s16x8*)(rkh + rr * 64 + l4 * 8);
      s16x8 b1 = *(const s16x8*)(rkh + rr * 64 + 32 + l4 * 8);
      f32x4 t0 = zero;
      t0 = mfma16(aq0, b0, t0);
      t0 = mfma16(aq1, b1, t0);
      #pragma unroll
      for (int j = 0; j < 4; j++) {
        const int row = w * 16 + l4 * 4 + j;
        *(short*)(bufb + row * 512 + ((rr * 2) ^ ((row & 7) << 4))) = f2bf(t0[j]);
      }
    }
  }
  // qr gather — wave-own rows, in-wave lgkmcnt ordering suffices
  #pragma unroll
  for (int n = 0; n < 4; n++)
    #pragma unroll
    for (int j = 0; j < 4; j++) {
      const int t = w * 16 + l4 * 4 + j, r = idxr[n * 4 + j];
      sacc[n][j] += bf2f(*(const short*)(bufb + t * 512 + ((r * 2) ^ ((t & 7) << 4))));
    }

  // kr = k @ rel_q[h]^T -> buf own rows (overwrites own qr, safe)
  {
    const int rowk = w * 16 + l15, kx = (rowk & 7) << 4;
    s16x8 ak0 = *(const s16x8*)(ksb + rowk * 128 + ((l4 * 16) ^ kx));
    s16x8 ak1 = *(const s16x8*)(ksb + rowk * 128 + ((64 + l4 * 16) ^ kx));
    const short* rqh = relqb + h * 240 * 64;
    #pragma unroll
    for (int n = 0; n < 15; n++) {
      const int rr = n * 16 + l15;
      s16x8 b0 = *(const s16x8*)(rqh + rr * 64 + l4 * 8);
      s16x8 b1 = *(const s16x8*)(rqh + rr * 64 + 32 + l4 * 8);
      f32x4 t0 = zero;
      t0 = mfma16(ak0, b0, t0);
      t0 = mfma16(ak1, b1, t0);
      #pragma unroll
      for (int j = 0; j < 4; j++) {
        const int row = w * 16 + l4 * 4 + j;
        *(short*)(bufb + row * 512 + ((rr * 2) ^ ((row & 7) << 4))) = f2bf(t0[j]);
      }
    }
  }
  __syncthreads();   // barrier B — all kr rows visible

  // kr gather (cross rows) + D + scale + softmax
  const float scale = 0.125f;
  float att[4][4];
  #pragma unroll
  for (int n = 0; n < 4; n++)
    #pragma unroll
    for (int j = 0; j < 4; j++) {
      const int s = n * 16 + l15, r = idxr[n * 4 + j];
      float kv = bf2f(*(const short*)(bufb + s * 512 + ((r * 2) ^ ((s & 7) << 4))));
      sacc[n][j] = (sacc[n][j] + kv + Ds[r]) * scale;
    }
  #pragma unroll
  for (int j = 0; j < 4; j++) {
    float m = fmaxf(fmaxf(sacc[0][j], sacc[1][j]), fmaxf(sacc[2][j], sacc[3][j]));
    m = fmaxf(m, __shfl_xor(m, 1));
    m = fmaxf(m, __shfl_xor(m, 2));
    m = fmaxf(m, __shfl_xor(m, 4));
    m = fmaxf(m, __shfl_xor(m, 8));
    float sum = 0.f;
    #pragma unroll
    for (int n = 0; n < 4; n++) { att[n][j] = __expf(sacc[n][j] - m); sum += att[n][j]; }
    sum += __shfl_xor(sum, 1);
    sum += __shfl_xor(sum, 2);
    sum += __shfl_xor(sum, 4);
    sum += __shfl_xor(sum, 8);
    const float inv = 1.f / sum;
    #pragma unroll
    for (int n = 0; n < 4; n++) att[n][j] *= inv;
  }
  // attn -> ks (own rows; all ks readers finished before barrier B)
  #pragma unroll
  for (int n = 0; n < 4; n++)
    #pragma unroll
    for (int j = 0; j < 4; j++) {
      const int t = w * 16 + l4 * 4 + j, s = n * 16 + l15;
      *(short*)(ksb + t * 128 + ((s * 2) ^ ((t & 7) << 4))) = f2bf(att[n][j]);
    }
  __syncthreads();   // barrier C — all kr-gather reads of buf done

  // zero own buf rows, then collision-free P scatter (own rows)
  {
    char* bz = bufb + w * 8192 + lane * 128;
    s16x8 z = {0, 0, 0, 0, 0, 0, 0, 0};
    #pragma unroll
    for (int i = 0; i < 8; i++) *(s16x8*)(bz + i * 16) = z;
  }
  #pragma unroll
  for (int n = 0; n < 4; n++)
    #pragma unroll
    for (int j = 0; j < 4; j++) {
      const int t = w * 16 + l4 * 4 + j, r = idxr[n * 4 + j];
      *(short*)(bufb + t * 512 + ((r * 2) ^ ((t & 7) << 4))) = f2bf(att[n][j]);
    }

  // out = attn @ v + P @ rel_v[h]
  f32x4 oacc[4];
  oacc[0] = oacc[1] = oacc[2] = oacc[3] = zero;
  {
    const int rowp = w * 16 + l15, px = (rowp & 7) << 4;
    s16x8 pa0 = *(const s16x8*)(ksb + rowp * 128 + ((l4 * 16) ^ px));
    s16x8 pa1 = *(const s16x8*)(ksb + rowp * 128 + ((64 + l4 * 16) ^ px));
    #pragma unroll
    for (int n = 0; n < 4; n++) {
      const int rv = n * 16 + l15, vx = (rv & 7) << 4;
      s16x8 b0 = *(const s16x8*)(vtb + rv * 128 + ((l4 * 16) ^ vx));
      s16x8 b1 = *(const s16x8*)(vtb + rv * 128 + ((64 + l4 * 16) ^ vx));
      oacc[n] = mfma16(pa0, b0, oacc[n]);
      oacc[n] = mfma16(pa1, b1, oacc[n]);
    }
    const short* rvh = relvT + h * 64 * 256;
    #pragma unroll
    for (int kk = 0; kk < 8; kk++) {
      s16x8 pa = *(const s16x8*)(bufb + rowp * 512 + ((kk * 64 + l4 * 16) ^ px));
      #pragma unroll
      for (int n = 0; n < 4; n++) {
        s16x8 bb = *(const s16x8*)(rvh + (n * 16 + l15) * 256 + kk * 32 + l4 * 8);
        oacc[n] = mfma16(pa, bb, oacc[n]);
      }
    }
  }
  #pragma unroll
  for (int n = 0; n < 4; n++)
    #pragma unroll
    for (int j = 0; j < 4; j++) {
      const int t = w * 16 + l4 * 4 + j, d = n * 16 + l15;
      outA[((long)(b * 64 + t)) * 1024 + h * 64 + d] = f2bf(oacc[n][j]);
    }
}

extern "C" void kernel_launch(void* const* d_in, const int* in_sizes, int n_in,
                              void* d_out, int out_size, void* d_ws, size_t ws_size,
                              hipStream_t stream) {
  const float* x     = (const float*)d_in[0];
  const float* Wq_w  = (const float*)d_in[1];
  const float* Wq_b  = (const float*)d_in[2];
  const float* Wk_w  = (const float*)d_in[3];
  const float* Wk_b  = (const float*)d_in[4];
  const float* Wv_w  = (const float*)d_in[5];
  const float* Wv_b  = (const float*)d_in[6];
  const float* Wo_w  = (const float*)d_in[7];
  const float* Wo_b  = (const float*)d_in[8];
  const float* rel_q = (const float*)d_in[9];
  const float* rel_k = (const float*)d_in[10];
  const float* rel_v = (const float*)d_in[11];
  const int* rel_index = (const int*)d_in[12];
  float* out = (float*)d_out;

  char* ws = (char*)d_ws;
  short* x_bf   = (short*)(ws);                   // 134,217,728 B (reused as a_bf)
  short* qkv_bf = (short*)(ws + 134217728L);      // 402,653,184 B
  short* wq_bf  = (short*)(ws + 536870912L);      // wq|wk|wv contiguous (2 MB each)
  short* wk_bf  = (short*)(ws + 538968064L);
  short* wv_bf  = (short*)(ws + 541065216L);
  short* wo_bf  = (short*)(ws + 543162368L);
  float* biascat= (float*)(ws + 545259520L);      // 12,288 B
  short* relqb  = (short*)(ws + 545271808L);      // 491,520 B
  short* relkb  = (short*)(ws + 545763328L);
  short* relvT  = (short*)(ws + 546254848L);      // 524,288 B
  float* Dh     = (float*)(ws + 546779136L);      // 15,360 B
  short* a_bf   = x_bf;  // x_bf dead after QKV GEMM

  cvt_bf16_kernel<<<65536, 256, 0, stream>>>(x, x_bf, 67108864L);
  cvt_bf16_kernel<<<1024, 256, 0, stream>>>(Wq_w, wq_bf, 1048576L);
  cvt_bf16_kernel<<<1024, 256, 0, stream>>>(Wk_w, wk_bf, 1048576L);
  cvt_bf16_kernel<<<1024, 256, 0, stream>>>(Wv_w, wv_bf, 1048576L);
  cvt_bf16_kernel<<<1024, 256, 0, stream>>>(Wo_w, wo_bf, 1048576L);
  bias_cat_kernel<<<12, 256, 0, stream>>>(Wq_b, Wk_b, Wv_b, biascat);
  prep_rel_kernel<<<3840, 64, 0, stream>>>(rel_q, rel_k, rel_v, relqb, relkb, relvT, Dh);
  // fused QKV projection: N = 3072 (wq|wk|wv contiguous)
  gemm_bt_kernel<1><<<12288, 256, 0, stream>>>(x_bf, wq_bf, biascat, (void*)qkv_bf,
                                               65536, 3072, 1024);
  attn_kernel<<<16384, 256, 0, stream>>>(qkv_bf, relqb, relkb, relvT, Dh, rel_index, a_bf);
  gemm_bt_kernel<0><<<4096, 256, 0, stream>>>(a_bf, wo_bf, Wo_b, (void*)out, 65536, 1024, 1024);
}